// Round 6
// baseline (327.836 us; speedup 1.0000x reference)
//
#include <hip/hip_runtime.h>
#include <cstdint>
#include <cstddef>

#define N_PIX   16384
#define K_EMB   8192
#define DDIM    256

// ws layout (bytes) — total 21,069,840
#define WS_ABF      0           // A bf16 pixel-major [16384][256]   8388608
#define WS_EBF      8388608     // E bf16 [8192][256]                4194304
#define WS_KEYS     12582912    // keys [16384][64] uint2            8388608
#define WS_ZSQ      20971520    // 16384*4
#define WS_ESQ      21037056    // 8192*4
#define WS_LOSS     21069824    // 8
#define WS_CNT      21069832    // 4

typedef short s16x8 __attribute__((ext_vector_type(8)));
typedef float f32x4 __attribute__((ext_vector_type(4)));

__device__ __forceinline__ unsigned int f32_sortable(float f) {
    unsigned int u = __float_as_uint(f);
    return (u & 0x80000000u) ? ~u : (u | 0x80000000u);
}

__device__ __forceinline__ unsigned short f2bf_rne(float x) {
    unsigned int u = __float_as_uint(x);
    unsigned int r = u + 0x7FFFu + ((u >> 16) & 1u);
    return (unsigned short)(r >> 16);
}

__device__ __forceinline__ void async16(const unsigned short* g, unsigned short* l) {
    __builtin_amdgcn_global_load_lds(
        (const __attribute__((address_space(1))) void*)g,
        (__attribute__((address_space(3))) void*)l, 16, 0, 0);
}

// ---------------------------------------------------------------- kernel 1
// Fused prep: blocks 0..511 transpose+convert z -> Abf + zsq (np pairwise);
// blocks 512..543 convert emb -> Ebf + esq (np pairwise). Zero loss+counter.
__global__ __launch_bounds__(256) void prep_kernel(
        const float* __restrict__ z, const float* __restrict__ emb,
        unsigned short* __restrict__ Abf, unsigned short* __restrict__ Ebf,
        float* __restrict__ zsq, float* __restrict__ esq,
        double* __restrict__ lossAcc, unsigned* __restrict__ doneCnt) {
    __shared__ float tile[32][257];
    int blk = blockIdx.x;
    int t   = threadIdx.x;
    if (blk < 512) {
        int b   = blk >> 5;
        int hw0 = (blk & 31) * 32;
        const float* zb = z + (size_t)b * 262144 + hw0;
        int px = t & 31;
        int cb = t >> 5;
#pragma unroll
        for (int cc = 0; cc < 32; ++cc) {
            int c = cc * 8 + cb;
            tile[px][c] = zb[(size_t)c * 1024 + px];
        }
        __syncthreads();
        int p0 = b * 1024 + hw0;
        int wv = t >> 6, lane = t & 63;
#pragma unroll
        for (int iter = 0; iter < 8; ++iter) {
            int pl = iter * 4 + wv;
            ushort4 o;
            o.x = f2bf_rne(tile[pl][lane * 4 + 0]);
            o.y = f2bf_rne(tile[pl][lane * 4 + 1]);
            o.z = f2bf_rne(tile[pl][lane * 4 + 2]);
            o.w = f2bf_rne(tile[pl][lane * 4 + 3]);
            ((ushort4*)(Abf + (size_t)(p0 + pl) * 256))[lane] = o;
        }
        if (t < 32) {
            float r[16];
#pragma unroll
            for (int j = 0; j < 16; ++j) r[j] = 0.f;
#pragma unroll
            for (int c = 0; c < 256; ++c) {
                float x  = tile[t][c];
                float sq = __fmul_rn(x, x);
                int slot = ((c >> 7) << 3) | (c & 7);
                r[slot] = __fadd_rn(r[slot], sq);
            }
            float h0 = __fadd_rn(
                __fadd_rn(__fadd_rn(r[0], r[1]), __fadd_rn(r[2], r[3])),
                __fadd_rn(__fadd_rn(r[4], r[5]), __fadd_rn(r[6], r[7])));
            float h1 = __fadd_rn(
                __fadd_rn(__fadd_rn(r[8], r[9]), __fadd_rn(r[10], r[11])),
                __fadd_rn(__fadd_rn(r[12], r[13]), __fadd_rn(r[14], r[15])));
            zsq[p0 + t] = __fadd_rn(h0, h1);
        }
        if (blk == 0 && t == 0) { *lossAcc = 0.0; *doneCnt = 0u; }
    } else {
        int k = (blk - 512) * 256 + t;
        const float* ep = emb + (size_t)k * DDIM;
        ushort4* eb = (ushort4*)(Ebf + (size_t)k * DDIM);
        float r[16];
#pragma unroll
        for (int j = 0; j < 16; ++j) r[j] = 0.f;
#pragma unroll
        for (int c4 = 0; c4 < 64; ++c4) {
            float4 v = ((const float4*)ep)[c4];
            ushort4 o;
            o.x = f2bf_rne(v.x); o.y = f2bf_rne(v.y);
            o.z = f2bf_rne(v.z); o.w = f2bf_rne(v.w);
            eb[c4] = o;
            int c = c4 * 4;
            { int slot = ((c >> 7) << 3) | (c & 7);
              r[slot] = __fadd_rn(r[slot], __fmul_rn(v.x, v.x)); }
            { int cc = c + 1; int slot = ((cc >> 7) << 3) | (cc & 7);
              r[slot] = __fadd_rn(r[slot], __fmul_rn(v.y, v.y)); }
            { int cc = c + 2; int slot = ((cc >> 7) << 3) | (cc & 7);
              r[slot] = __fadd_rn(r[slot], __fmul_rn(v.z, v.z)); }
            { int cc = c + 3; int slot = ((cc >> 7) << 3) | (cc & 7);
              r[slot] = __fadd_rn(r[slot], __fmul_rn(v.w, v.w)); }
        }
        float h0 = __fadd_rn(
            __fadd_rn(__fadd_rn(r[0], r[1]), __fadd_rn(r[2], r[3])),
            __fadd_rn(__fadd_rn(r[4], r[5]), __fadd_rn(r[6], r[7])));
        float h1 = __fadd_rn(
            __fadd_rn(__fadd_rn(r[8], r[9]), __fadd_rn(r[10], r[11])),
            __fadd_rn(__fadd_rn(r[12], r[13]), __fadd_rn(r[14], r[15])));
        esq[k] = __fadd_rn(h0, h1);
    }
}

// ---------------------------------------------------------------- kernel 2
// bf16 MFMA GEMM: 512 threads, tile 128 px x 256 cand, BK=32, dbuf DMA.
// 8 waves (wm 0..1 x wn 0..3), each 64x64 via 4x4 frags of 16x16x32.
// Epilogue: top-2 per (pixel, 128-cand half) via shfl(8) pre-merge +
// stride-17 u32 planes (conflict-free). keys[p][64] uint2 (pixel-major).
__global__ __launch_bounds__(512) void mfma_score_kernel(
        const unsigned short* __restrict__ Abf,
        const unsigned short* __restrict__ Ebf,
        const float* __restrict__ esq,
        unsigned int* __restrict__ keys) {
    union SM {
        struct { unsigned short As[2][4096]; unsigned short Bs[2][8192]; } k; // 48K
        struct { unsigned pa[2][128][17]; unsigned pb[2][128][17]; } e;       // 34816
    };
    __shared__ SM sm;
    __shared__ float sEp[256];

    const int nb2 = blockIdx.x;    // 256-cand block, 0..31
    const int mb  = blockIdx.y;    // 128-px block, 0..127
    const int t = threadIdx.x;     // 0..511
    const int w = t >> 6, lane = t & 63;
    const int wm = w >> 2, wn = w & 3;
    const int quad = lane >> 4, l16 = lane & 15;

    if (t < 256)
        sEp[t] = (esq[nb2 * 256 + t] + 0.125f) * 2097152.0f;  // (esq+1/8)*2^21

    // staging chunk maps (16B chunks, slot-XOR swizzle)
    const int ra  = t >> 2,           sa  = (t & 3) ^ ((ra ^ (ra >> 2)) & 3);
    const int cb0 = t,                rb0 = cb0 >> 2;
    const int sb0 = (cb0 & 3) ^ ((rb0 ^ (rb0 >> 2)) & 3);
    const int cb1 = t + 512,          rb1 = cb1 >> 2;
    const int sb1 = (cb1 & 3) ^ ((rb1 ^ (rb1 >> 2)) & 3);

    const unsigned short* Ag = Abf + (size_t)(mb * 128) * 256;
    const unsigned short* Eg = Ebf + (size_t)(nb2 * 256) * 256;
    const unsigned short* ag  = Ag + (size_t)ra  * 256 + sa  * 8;
    const unsigned short* e0g = Eg + (size_t)rb0 * 256 + sb0 * 8;
    const unsigned short* e1g = Eg + (size_t)rb1 * 256 + sb1 * 8;

    f32x4 acc[4][4];
#pragma unroll
    for (int i = 0; i < 4; ++i)
#pragma unroll
        for (int j = 0; j < 4; ++j)
#pragma unroll
            for (int r = 0; r < 4; ++r) acc[i][j][r] = 0.f;

    // prologue DMA into buffer 0
    async16(ag,  &sm.k.As[0][t * 8]);
    async16(e0g, &sm.k.Bs[0][cb0 * 8]);
    async16(e1g, &sm.k.Bs[0][cb1 * 8]);

#pragma unroll
    for (int it = 0; it < 8; ++it) {
        const int cur = it & 1, nxt = cur ^ 1;
        __syncthreads();
        if (it < 7) {
            const int k0n = (it + 1) * 32;
            async16(ag + k0n,  &sm.k.As[nxt][t * 8]);
            async16(e0g + k0n, &sm.k.Bs[nxt][cb0 * 8]);
            async16(e1g + k0n, &sm.k.Bs[nxt][cb1 * 8]);
        }
        s16x8 af[4], bfr[4];
#pragma unroll
        for (int fi = 0; fi < 4; ++fi) {
            int row  = wm * 64 + fi * 16 + l16;
            int slot = quad ^ ((row ^ (row >> 2)) & 3);
            af[fi] = *(const s16x8*)&sm.k.As[cur][row * 32 + slot * 8];
        }
#pragma unroll
        for (int fj = 0; fj < 4; ++fj) {
            int row  = wn * 64 + fj * 16 + l16;
            int slot = quad ^ ((row ^ (row >> 2)) & 3);
            bfr[fj] = *(const s16x8*)&sm.k.Bs[cur][row * 32 + slot * 8];
        }
#pragma unroll
        for (int fi = 0; fi < 4; ++fi)
#pragma unroll
            for (int fj = 0; fj < 4; ++fj)
                acc[fi][fj] = __builtin_amdgcn_mfma_f32_16x16x32_bf16(
                    af[fi], bfr[fj], acc[fi][fj], 0, 0, 0);
    }

    __syncthreads();   // K-loop LDS reads done; alias staging as planes

    float epv[4];
    unsigned idxc[4];
#pragma unroll
    for (int fj = 0; fj < 4; ++fj) {
        int nloc = wn * 64 + fj * 16 + l16;
        epv[fj]  = sEp[nloc];
        idxc[fj] = (unsigned)(nb2 * 256 + nloc);
    }
    const int slot_o = wn >> 1;          // which 128-cand half
    const int cb8    = (wn & 1) * 8;     // col base after l16^8 pre-merge

    // phase A: pack, top2-of-4(fj), shfl(8) pair-merge, store to planes
#pragma unroll
    for (int fi = 0; fi < 4; ++fi) {
#pragma unroll
        for (int r = 0; r < 4; ++r) {
            unsigned kk[4];
#pragma unroll
            for (int fj = 0; fj < 4; ++fj) {
                unsigned u = (unsigned)fmaf(acc[fi][fj][r], -4194304.0f, epv[fj]);
                kk[fj] = (u << 13) | idxc[fj];
            }
            unsigned lo0 = min(kk[0], kk[1]), hi0 = max(kk[0], kk[1]);
            unsigned lo1 = min(kk[2], kk[3]), hi1 = max(kk[2], kk[3]);
            unsigned a0 = min(lo0, lo1);
            unsigned a1 = min(max(lo0, lo1), min(hi0, hi1));
            unsigned o0 = (unsigned)__shfl_xor((int)a0, 8, 64);
            unsigned o1 = (unsigned)__shfl_xor((int)a1, 8, 64);
            unsigned n0 = min(a0, o0);
            unsigned n1 = min(max(a0, o0), min(a1, o1));
            if (l16 < 8) {
                int row = wm * 64 + fi * 16 + quad * 4 + r;
                sm.e.pa[slot_o][row][cb8 + l16] = n0;
                sm.e.pb[slot_o][row][cb8 + l16] = n1;
            }
        }
    }
    __syncthreads();

    // phase B: one thread per (slot,row): top2 over 16 cols, write key
    if (t < 256) {
        int so = t >> 7, row = t & 127;
        const unsigned* pav = sm.e.pa[so][row];
        const unsigned* pbv = sm.e.pb[so][row];
        unsigned m0 = pav[0], m1 = pbv[0];
#pragma unroll
        for (int i = 1; i < 16; ++i) {
            unsigned a = pav[i], b = pbv[i];
            unsigned n0 = min(m0, a);
            unsigned n1 = min(max(m0, a), min(m1, b));
            m0 = n0; m1 = n1;
        }
        ((uint2*)keys)[(size_t)(mb * 128 + row) * 64 + nb2 * 2 + so] =
            make_uint2(m0, m1);
    }
}

// ---------------------------------------------------------------- kernel 3
// Fused: per-(b,h) block of 32 pixels — LDS z-tile, keys min + margin
// candidates (ballot), exact rescore (fp64 dot -> np fp32), idx out,
// gather emb[idx] -> out, loss accumulation + last-block loss finalize.
__global__ __launch_bounds__(256) void final_kernel(
        const unsigned int* __restrict__ keys,
        const float* __restrict__ z, const float* __restrict__ emb,
        const float* __restrict__ zsq, const float* __restrict__ esq,
        float* __restrict__ out, float* __restrict__ idx_out,
        float* __restrict__ loss_out,
        double* __restrict__ lossAcc, unsigned* __restrict__ doneCnt) {
    __shared__ float ztile[32][260];
    __shared__ int sidx[32];
    int blk = blockIdx.x;            // 0..511
    int b = blk >> 5, h = blk & 31;
    int t = threadIdx.x;
    int p0 = b * 1024 + h * 32;
    const float* zb = z + (size_t)b * 262144 + h * 32;
    {
        int px = t & 31, cb = t >> 5;
#pragma unroll
        for (int cc = 0; cc < 32; ++cc) {
            int c = cc * 8 + cb;
            ztile[px][c] = zb[(size_t)c * 1024 + px];
        }
    }
    __syncthreads();

    int wq = t >> 6, lane = t & 63;
    const uint2* kp = (const uint2*)keys;
#pragma unroll 1
    for (int i = 0; i < 8; ++i) {
        int px = wq * 8 + i;
        int p  = p0 + px;
        uint2 kv = kp[(size_t)p * 64 + lane];
        unsigned m = min(kv.x, kv.y);
#pragma unroll
        for (int off = 32; off >= 1; off >>= 1)
            m = min(m, (unsigned)__shfl_xor((int)m, off, 64));
        unsigned thr = (m >> 13) + 512;   // margin 512*2^-21 = 2.44e-4
        unsigned long long m0 = __ballot((kv.x >> 13) <= thr);
        unsigned long long m1 = __ballot((kv.y >> 13) <= thr);
        float4 zv = *(const float4*)&ztile[px][lane * 4];
        float zs = zsq[p];
        unsigned long long best = ~0ull;
        while (m0 | m1) {
            bool use0 = (m0 != 0);
            unsigned long long mm = use0 ? m0 : m1;
            int src = (int)__builtin_ctzll(mm);
            if (use0) m0 &= m0 - 1; else m1 &= m1 - 1;
            unsigned keyv = (unsigned)__shfl((int)(use0 ? kv.x : kv.y), src, 64);
            int k = (int)(keyv & 0x1FFFu);
            const float4 ev = *(const float4*)(emb + (size_t)k * DDIM + lane * 4);
            double d = (double)zv.x * ev.x + (double)zv.y * ev.y
                     + (double)zv.z * ev.z + (double)zv.w * ev.w;
#pragma unroll
            for (int off = 32; off >= 1; off >>= 1)
                d += __shfl_down(d, off, 64);
            d = __shfl(d, 0, 64);
            float df = (float)d;
            float s  = __fsub_rn(__fadd_rn(zs, esq[k]), __fmul_rn(2.0f, df));
            unsigned long long key =
                ((unsigned long long)f32_sortable(s) << 32) | (unsigned)k;
            best = key < best ? key : best;
        }
        if (lane == 0) {
            int k = (int)(unsigned)(best & 0xffffffffu);
            sidx[px] = k;
            idx_out[p] = (float)k;
        }
    }
    __syncthreads();

    // gather + loss (z from LDS)
    int wq2 = t & 31, cy = t >> 5;
    int kk = sidx[wq2];
    const float* er = emb + (size_t)kk * DDIM;
    float* ob = out + (size_t)b * 262144 + h * 32;
    float local = 0.f;
#pragma unroll 4
    for (int it = 0; it < 32; ++it) {
        int c = it * 8 + cy;
        float q = er[c];
        float d = q - ztile[wq2][c];
        ob[(size_t)c * 1024 + wq2] = q;
        local += d * d;
    }
#pragma unroll
    for (int off = 32; off >= 1; off >>= 1) local += __shfl_down(local, off, 64);
    __shared__ float wsum[4];
    if ((t & 63) == 0) wsum[t >> 6] = local;
    __syncthreads();
    if (t == 0) {
        double s = (double)wsum[0] + (double)wsum[1]
                 + (double)wsum[2] + (double)wsum[3];
        atomicAdd(lossAcc, s);
        __threadfence();
        unsigned old = atomicAdd(doneCnt, 1u);
        if (old == 511u) {
            double tot = atomicAdd(lossAcc, 0.0);  // coherent device-scope read
            *loss_out = (float)(tot * (1.25 / 4194304.0));
        }
    }
}

// ----------------------------------------------------------------
extern "C" void kernel_launch(void* const* d_in, const int* in_sizes, int n_in,
                              void* d_out, int out_size, void* d_ws, size_t ws_size,
                              hipStream_t stream) {
    const float* z   = (const float*)d_in[0];
    const float* emb = (const float*)d_in[1];
    float* out = (float*)d_out;
    char* ws = (char*)d_ws;

    unsigned short* Abf = (unsigned short*)(ws + WS_ABF);
    unsigned short* Ebf = (unsigned short*)(ws + WS_EBF);
    unsigned int*  keys = (unsigned int*)(ws + WS_KEYS);
    float* zsq      = (float*)(ws + WS_ZSQ);
    float* esq      = (float*)(ws + WS_ESQ);
    double* lossAcc = (double*)(ws + WS_LOSS);
    unsigned* doneCnt = (unsigned*)(ws + WS_CNT);

    prep_kernel<<<544, 256, 0, stream>>>(z, emb, Abf, Ebf, zsq, esq,
                                         lossAcc, doneCnt);
    mfma_score_kernel<<<dim3(32, 128), 512, 0, stream>>>(Abf, Ebf, esq, keys);
    final_kernel<<<512, 256, 0, stream>>>(keys, z, emb, zsq, esq,
                                          out, out + 4194305, out + 4194304,
                                          lossAcc, doneCnt);
}

// Round 7
// 304.781 us; speedup vs baseline: 1.0756x; 1.0756x over previous
//
#include <hip/hip_runtime.h>
#include <cstdint>
#include <cstddef>

#define N_PIX   16384
#define K_EMB   8192
#define DDIM    256

// ws layout (bytes) — total 21,069,840
#define WS_ABF      0           // A bf16 pixel-major [16384][256]   8388608
#define WS_EBF      8388608     // E bf16 [8192][256]                4194304
#define WS_KEYS     12582912    // keys [16384][64] uint2            8388608
#define WS_ZSQ      20971520    // 16384*4
#define WS_ESQ      21037056    // 8192*4
#define WS_LOSS     21069824    // 8
#define WS_CNT      21069832    // 4

typedef short s16x8 __attribute__((ext_vector_type(8)));
typedef float f32x4 __attribute__((ext_vector_type(4)));

__device__ __forceinline__ unsigned int f32_sortable(float f) {
    unsigned int u = __float_as_uint(f);
    return (u & 0x80000000u) ? ~u : (u | 0x80000000u);
}

__device__ __forceinline__ unsigned short f2bf_rne(float x) {
    unsigned int u = __float_as_uint(x);
    unsigned int r = u + 0x7FFFu + ((u >> 16) & 1u);
    return (unsigned short)(r >> 16);
}

__device__ __forceinline__ void async16(const unsigned short* g, unsigned short* l) {
    __builtin_amdgcn_global_load_lds(
        (const __attribute__((address_space(1))) void*)g,
        (__attribute__((address_space(3))) void*)l, 16, 0, 0);
}

// ---------------------------------------------------------------- kernel 1
// Fused prep: blocks 0..511 transpose+convert z -> Abf + zsq (np pairwise);
// blocks 512..543 convert emb -> Ebf + esq (np pairwise). Zero loss+counter.
__global__ __launch_bounds__(256) void prep_kernel(
        const float* __restrict__ z, const float* __restrict__ emb,
        unsigned short* __restrict__ Abf, unsigned short* __restrict__ Ebf,
        float* __restrict__ zsq, float* __restrict__ esq,
        double* __restrict__ lossAcc, unsigned* __restrict__ doneCnt) {
    __shared__ float tile[32][257];
    int blk = blockIdx.x;
    int t   = threadIdx.x;
    if (blk < 512) {
        int b   = blk >> 5;
        int hw0 = (blk & 31) * 32;
        const float* zb = z + (size_t)b * 262144 + hw0;
        int px = t & 31;
        int cb = t >> 5;
#pragma unroll
        for (int cc = 0; cc < 32; ++cc) {
            int c = cc * 8 + cb;
            tile[px][c] = zb[(size_t)c * 1024 + px];
        }
        __syncthreads();
        int p0 = b * 1024 + hw0;
        int wv = t >> 6, lane = t & 63;
#pragma unroll
        for (int iter = 0; iter < 8; ++iter) {
            int pl = iter * 4 + wv;
            ushort4 o;
            o.x = f2bf_rne(tile[pl][lane * 4 + 0]);
            o.y = f2bf_rne(tile[pl][lane * 4 + 1]);
            o.z = f2bf_rne(tile[pl][lane * 4 + 2]);
            o.w = f2bf_rne(tile[pl][lane * 4 + 3]);
            ((ushort4*)(Abf + (size_t)(p0 + pl) * 256))[lane] = o;
        }
        if (t < 32) {
            float r[16];
#pragma unroll
            for (int j = 0; j < 16; ++j) r[j] = 0.f;
#pragma unroll
            for (int c = 0; c < 256; ++c) {
                float x  = tile[t][c];
                float sq = __fmul_rn(x, x);
                int slot = ((c >> 7) << 3) | (c & 7);
                r[slot] = __fadd_rn(r[slot], sq);
            }
            float h0 = __fadd_rn(
                __fadd_rn(__fadd_rn(r[0], r[1]), __fadd_rn(r[2], r[3])),
                __fadd_rn(__fadd_rn(r[4], r[5]), __fadd_rn(r[6], r[7])));
            float h1 = __fadd_rn(
                __fadd_rn(__fadd_rn(r[8], r[9]), __fadd_rn(r[10], r[11])),
                __fadd_rn(__fadd_rn(r[12], r[13]), __fadd_rn(r[14], r[15])));
            zsq[p0 + t] = __fadd_rn(h0, h1);
        }
        if (blk == 0 && t == 0) { *lossAcc = 0.0; *doneCnt = 0u; }
    } else {
        int k = (blk - 512) * 256 + t;
        const float* ep = emb + (size_t)k * DDIM;
        ushort4* eb = (ushort4*)(Ebf + (size_t)k * DDIM);
        float r[16];
#pragma unroll
        for (int j = 0; j < 16; ++j) r[j] = 0.f;
#pragma unroll
        for (int c4 = 0; c4 < 64; ++c4) {
            float4 v = ((const float4*)ep)[c4];
            ushort4 o;
            o.x = f2bf_rne(v.x); o.y = f2bf_rne(v.y);
            o.z = f2bf_rne(v.z); o.w = f2bf_rne(v.w);
            eb[c4] = o;
            int c = c4 * 4;
            { int slot = ((c >> 7) << 3) | (c & 7);
              r[slot] = __fadd_rn(r[slot], __fmul_rn(v.x, v.x)); }
            { int cc = c + 1; int slot = ((cc >> 7) << 3) | (cc & 7);
              r[slot] = __fadd_rn(r[slot], __fmul_rn(v.y, v.y)); }
            { int cc = c + 2; int slot = ((cc >> 7) << 3) | (cc & 7);
              r[slot] = __fadd_rn(r[slot], __fmul_rn(v.z, v.z)); }
            { int cc = c + 3; int slot = ((cc >> 7) << 3) | (cc & 7);
              r[slot] = __fadd_rn(r[slot], __fmul_rn(v.w, v.w)); }
        }
        float h0 = __fadd_rn(
            __fadd_rn(__fadd_rn(r[0], r[1]), __fadd_rn(r[2], r[3])),
            __fadd_rn(__fadd_rn(r[4], r[5]), __fadd_rn(r[6], r[7])));
        float h1 = __fadd_rn(
            __fadd_rn(__fadd_rn(r[8], r[9]), __fadd_rn(r[10], r[11])),
            __fadd_rn(__fadd_rn(r[12], r[13]), __fadd_rn(r[14], r[15])));
        esq[k] = __fadd_rn(h0, h1);
    }
}

// ---------------------------------------------------------------- kernel 2
// bf16 MFMA GEMM — R5 shape (256 thr, 128x128 tile, BK=32, dbuf DMA) with
// conflict-free epilogue: shfl_xor(8) pre-merge + u32 planes stride 17.
__global__ __launch_bounds__(256) void mfma_score_kernel(
        const unsigned short* __restrict__ Abf,
        const unsigned short* __restrict__ Ebf,
        const float* __restrict__ esq,
        unsigned int* __restrict__ keys) {
    union SM {
        struct { unsigned short As[2][4096]; unsigned short Bs[2][4096]; } k; // 32768
        struct { unsigned pa[128][17]; unsigned pb[128][17]; } e;             // 17408
    };
    __shared__ SM sm;
    __shared__ float sEp[128];

    const int nb = blockIdx.x;     // candidate block 0..63
    const int mb = blockIdx.y;     // pixel block 0..127
    const int t = threadIdx.x;
    const int w = t >> 6, lane = t & 63;
    const int wm = w >> 1, wn = w & 1;
    const int quad = lane >> 4, l16 = lane & 15;

    if (t < 128)
        sEp[t] = (esq[nb * 128 + t] + 0.125f) * 2097152.0f;  // (esq+1/8)*2^21

    // staging chunks: chunk c -> row=c>>2, slot=c&3 holds global sub=slot^swz(row)
    const int c0 = t, c1 = t + 256;
    const int r0 = c0 >> 2, s0 = (c0 & 3) ^ ((r0 ^ (r0 >> 2)) & 3);
    const int r1 = c1 >> 2, s1 = (c1 & 3) ^ ((r1 ^ (r1 >> 2)) & 3);

    const unsigned short* Ag = Abf + (size_t)(mb * 128) * 256;
    const unsigned short* Eg = Ebf + (size_t)(nb * 128) * 256;
    const unsigned short* a0g = Ag + (size_t)r0 * 256 + s0 * 8;
    const unsigned short* a1g = Ag + (size_t)r1 * 256 + s1 * 8;
    const unsigned short* e0g = Eg + (size_t)r0 * 256 + s0 * 8;
    const unsigned short* e1g = Eg + (size_t)r1 * 256 + s1 * 8;

    f32x4 acc[4][4];
#pragma unroll
    for (int i = 0; i < 4; ++i)
#pragma unroll
        for (int j = 0; j < 4; ++j)
#pragma unroll
            for (int r = 0; r < 4; ++r) acc[i][j][r] = 0.f;

    // prologue: DMA iter 0 into buffer 0
    async16(a0g, &sm.k.As[0][c0 * 8]);
    async16(a1g, &sm.k.As[0][c1 * 8]);
    async16(e0g, &sm.k.Bs[0][c0 * 8]);
    async16(e1g, &sm.k.Bs[0][c1 * 8]);

#pragma unroll
    for (int it = 0; it < 8; ++it) {
        const int cur = it & 1, nxt = cur ^ 1;
        __syncthreads();
        if (it < 7) {
            const int k0n = (it + 1) * 32;
            async16(a0g + k0n, &sm.k.As[nxt][c0 * 8]);
            async16(a1g + k0n, &sm.k.As[nxt][c1 * 8]);
            async16(e0g + k0n, &sm.k.Bs[nxt][c0 * 8]);
            async16(e1g + k0n, &sm.k.Bs[nxt][c1 * 8]);
        }
        s16x8 af[4], bfr[4];
#pragma unroll
        for (int fi = 0; fi < 4; ++fi) {
            int row  = wm * 64 + fi * 16 + l16;
            int slot = quad ^ ((row ^ (row >> 2)) & 3);
            af[fi] = *(const s16x8*)&sm.k.As[cur][row * 32 + slot * 8];
        }
#pragma unroll
        for (int fj = 0; fj < 4; ++fj) {
            int row  = wn * 64 + fj * 16 + l16;
            int slot = quad ^ ((row ^ (row >> 2)) & 3);
            bfr[fj] = *(const s16x8*)&sm.k.Bs[cur][row * 32 + slot * 8];
        }
#pragma unroll
        for (int fi = 0; fi < 4; ++fi)
#pragma unroll
            for (int fj = 0; fj < 4; ++fj)
                acc[fi][fj] = __builtin_amdgcn_mfma_f32_16x16x32_bf16(
                    af[fi], bfr[fj], acc[fi][fj], 0, 0, 0);
    }

    __syncthreads();   // K-loop LDS reads done; safe to alias staging as planes

    float epv[4];
    unsigned idxc[4];
#pragma unroll
    for (int fj = 0; fj < 4; ++fj) {
        int nloc = wn * 64 + fj * 16 + l16;
        epv[fj]  = sEp[nloc];
        idxc[fj] = (unsigned)(nb * 128 + nloc);
    }

    // phase A: pack, top2-of-4(fj), shfl_xor(8) pair-merge, store planes
#pragma unroll
    for (int fi = 0; fi < 4; ++fi) {
#pragma unroll
        for (int r = 0; r < 4; ++r) {
            unsigned kk[4];
#pragma unroll
            for (int fj = 0; fj < 4; ++fj) {
                unsigned u = (unsigned)fmaf(acc[fi][fj][r], -4194304.0f, epv[fj]);
                kk[fj] = (u << 13) | idxc[fj];
            }
            unsigned lo0 = min(kk[0], kk[1]), hi0 = max(kk[0], kk[1]);
            unsigned lo1 = min(kk[2], kk[3]), hi1 = max(kk[2], kk[3]);
            unsigned a0 = min(lo0, lo1);
            unsigned a1 = min(max(lo0, lo1), min(hi0, hi1));
            unsigned o0 = (unsigned)__shfl_xor((int)a0, 8, 64);
            unsigned o1 = (unsigned)__shfl_xor((int)a1, 8, 64);
            unsigned n0 = min(a0, o0);
            unsigned n1 = min(max(a0, o0), min(a1, o1));
            if (l16 < 8) {
                int row = wm * 64 + fi * 16 + quad * 4 + r;
                sm.e.pa[row][wn * 8 + l16] = n0;
                sm.e.pb[row][wn * 8 + l16] = n1;
            }
        }
    }
    __syncthreads();

    // phase B: one thread per row: top-2 over 16 col-pairs, write key
    if (t < 128) {
        const unsigned* pav = sm.e.pa[t];
        const unsigned* pbv = sm.e.pb[t];
        unsigned m0 = pav[0], m1 = pbv[0];
#pragma unroll
        for (int i = 1; i < 16; ++i) {
            unsigned a = pav[i], b = pbv[i];
            unsigned n0 = min(m0, a);
            unsigned n1 = min(max(m0, a), min(m1, b));
            m0 = n0; m1 = n1;
        }
        ((uint2*)keys)[(size_t)(mb * 128 + t) * 64 + nb] = make_uint2(m0, m1);
    }
}

// ---------------------------------------------------------------- kernel 3
// Fused: per 16-pixel block — LDS z-tile, keys min + margin candidates
// (ballot), exact rescore (fp64 dot -> np fp32), idx out, gather emb[idx]
// -> out, loss accumulation + last-block loss finalize.
__global__ __launch_bounds__(256) void final_kernel(
        const unsigned int* __restrict__ keys,
        const float* __restrict__ z, const float* __restrict__ emb,
        const float* __restrict__ zsq, const float* __restrict__ esq,
        float* __restrict__ out, float* __restrict__ idx_out,
        float* __restrict__ loss_out,
        double* __restrict__ lossAcc, unsigned* __restrict__ doneCnt) {
    __shared__ float ztile[16][260];
    __shared__ int sidx[16];
    int blk = blockIdx.x;            // 0..1023 = b*64 + hh (hh = 16-px group)
    int b = blk >> 6, hh = blk & 63;
    int t = threadIdx.x;
    int p0 = b * 1024 + hh * 16;
    const float* zb = z + (size_t)b * 262144 + hh * 16;
    {
        int px = t & 15, cb = t >> 4;    // cb 0..15
#pragma unroll
        for (int cc = 0; cc < 16; ++cc) {
            int c = cc * 16 + cb;
            ztile[px][c] = zb[(size_t)c * 1024 + px];
        }
    }
    __syncthreads();

    int wq = t >> 6, lane = t & 63;
    const uint2* kp = (const uint2*)keys;
#pragma unroll 1
    for (int i = 0; i < 4; ++i) {
        int px = wq * 4 + i;
        int p  = p0 + px;
        uint2 kv = kp[(size_t)p * 64 + lane];
        unsigned m = min(kv.x, kv.y);
#pragma unroll
        for (int off = 32; off >= 1; off >>= 1)
            m = min(m, (unsigned)__shfl_xor((int)m, off, 64));
        unsigned thr = (m >> 13) + 512;   // margin 512*2^-21 = 2.44e-4
        unsigned long long m0 = __ballot((kv.x >> 13) <= thr);
        unsigned long long m1 = __ballot((kv.y >> 13) <= thr);
        float4 zv = *(const float4*)&ztile[px][lane * 4];
        float zs = zsq[p];
        unsigned long long best = ~0ull;
        while (m0 | m1) {
            bool use0 = (m0 != 0);
            unsigned long long mm = use0 ? m0 : m1;
            int src = (int)__builtin_ctzll(mm);
            if (use0) m0 &= m0 - 1; else m1 &= m1 - 1;
            unsigned keyv = (unsigned)__shfl((int)(use0 ? kv.x : kv.y), src, 64);
            int k = (int)(keyv & 0x1FFFu);
            const float4 ev = *(const float4*)(emb + (size_t)k * DDIM + lane * 4);
            double d = (double)zv.x * ev.x + (double)zv.y * ev.y
                     + (double)zv.z * ev.z + (double)zv.w * ev.w;
#pragma unroll
            for (int off = 32; off >= 1; off >>= 1)
                d += __shfl_down(d, off, 64);
            d = __shfl(d, 0, 64);
            float df = (float)d;
            float s  = __fsub_rn(__fadd_rn(zs, esq[k]), __fmul_rn(2.0f, df));
            unsigned long long key =
                ((unsigned long long)f32_sortable(s) << 32) | (unsigned)k;
            best = key < best ? key : best;
        }
        if (lane == 0) {
            int k = (int)(unsigned)(best & 0xffffffffu);
            sidx[px] = k;
            idx_out[p] = (float)k;
        }
    }
    __syncthreads();

    // gather + loss (z from LDS)
    int px2 = t & 15, cy = t >> 4;       // cy 0..15
    int kk = sidx[px2];
    const float* er = emb + (size_t)kk * DDIM;
    float* ob = out + (size_t)b * 262144 + hh * 16;
    float local = 0.f;
#pragma unroll 4
    for (int it = 0; it < 16; ++it) {
        int c = it * 16 + cy;
        float q = er[c];
        float d = q - ztile[px2][c];
        ob[(size_t)c * 1024 + px2] = q;
        local += d * d;
    }
#pragma unroll
    for (int off = 32; off >= 1; off >>= 1) local += __shfl_down(local, off, 64);
    __shared__ float wsum[4];
    if ((t & 63) == 0) wsum[t >> 6] = local;
    __syncthreads();
    if (t == 0) {
        double s = (double)wsum[0] + (double)wsum[1]
                 + (double)wsum[2] + (double)wsum[3];
        atomicAdd(lossAcc, s);
        __threadfence();
        unsigned old = atomicAdd(doneCnt, 1u);
        if (old == 1023u) {
            double tot = atomicAdd(lossAcc, 0.0);  // coherent device-scope read
            *loss_out = (float)(tot * (1.25 / 4194304.0));
        }
    }
}

// ----------------------------------------------------------------
extern "C" void kernel_launch(void* const* d_in, const int* in_sizes, int n_in,
                              void* d_out, int out_size, void* d_ws, size_t ws_size,
                              hipStream_t stream) {
    const float* z   = (const float*)d_in[0];
    const float* emb = (const float*)d_in[1];
    float* out = (float*)d_out;
    char* ws = (char*)d_ws;

    unsigned short* Abf = (unsigned short*)(ws + WS_ABF);
    unsigned short* Ebf = (unsigned short*)(ws + WS_EBF);
    unsigned int*  keys = (unsigned int*)(ws + WS_KEYS);
    float* zsq      = (float*)(ws + WS_ZSQ);
    float* esq      = (float*)(ws + WS_ESQ);
    double* lossAcc = (double*)(ws + WS_LOSS);
    unsigned* doneCnt = (unsigned*)(ws + WS_CNT);

    prep_kernel<<<544, 256, 0, stream>>>(z, emb, Abf, Ebf, zsq, esq,
                                         lossAcc, doneCnt);
    mfma_score_kernel<<<dim3(64, 128), 256, 0, stream>>>(Abf, Ebf, esq, keys);
    final_kernel<<<1024, 256, 0, stream>>>(keys, z, emb, zsq, esq,
                                           out, out + 4194305, out + 4194304,
                                           lossAcc, doneCnt);
}

// Round 8
// 234.288 us; speedup vs baseline: 1.3993x; 1.3009x over previous
//
#include <hip/hip_runtime.h>
#include <cstdint>
#include <cstddef>

#define N_PIX   16384
#define K_EMB   8192
#define DDIM    256

// ws layout (bytes) — total 21,069,840
#define WS_ABF      0           // A bf16 pixel-major [16384][256]   8388608
#define WS_EBF      8388608     // E bf16 [8192][256]                4194304
#define WS_KEYS     12582912    // keys [16384][64] uint2            8388608
#define WS_ZSQ      20971520    // 16384*4
#define WS_ESQ      21037056    // 8192*4
#define WS_LOSS     21069824    // 8
#define WS_CNT      21069832    // 4

typedef short s16x8 __attribute__((ext_vector_type(8)));
typedef float f32x4 __attribute__((ext_vector_type(4)));

__device__ __forceinline__ unsigned int f32_sortable(float f) {
    unsigned int u = __float_as_uint(f);
    return (u & 0x80000000u) ? ~u : (u | 0x80000000u);
}

__device__ __forceinline__ unsigned short f2bf_rne(float x) {
    unsigned int u = __float_as_uint(x);
    unsigned int r = u + 0x7FFFu + ((u >> 16) & 1u);
    return (unsigned short)(r >> 16);
}

__device__ __forceinline__ void async16(const unsigned short* g, unsigned short* l) {
    __builtin_amdgcn_global_load_lds(
        (const __attribute__((address_space(1))) void*)g,
        (__attribute__((address_space(3))) void*)l, 16, 0, 0);
}

// ---------------------------------------------------------------- kernel 1
// Fused prep: blocks 0..511 transpose+convert z -> Abf + zsq (np pairwise);
// blocks 512..543 convert emb -> Ebf + esq (np pairwise). Zero loss+counter.
__global__ __launch_bounds__(256) void prep_kernel(
        const float* __restrict__ z, const float* __restrict__ emb,
        unsigned short* __restrict__ Abf, unsigned short* __restrict__ Ebf,
        float* __restrict__ zsq, float* __restrict__ esq,
        double* __restrict__ lossAcc, unsigned* __restrict__ doneCnt) {
    __shared__ float tile[32][257];
    int blk = blockIdx.x;
    int t   = threadIdx.x;
    if (blk < 512) {
        int b   = blk >> 5;
        int hw0 = (blk & 31) * 32;
        const float* zb = z + (size_t)b * 262144 + hw0;
        int px = t & 31;
        int cb = t >> 5;
#pragma unroll
        for (int cc = 0; cc < 32; ++cc) {
            int c = cc * 8 + cb;
            tile[px][c] = zb[(size_t)c * 1024 + px];
        }
        __syncthreads();
        int p0 = b * 1024 + hw0;
        int wv = t >> 6, lane = t & 63;
#pragma unroll
        for (int iter = 0; iter < 8; ++iter) {
            int pl = iter * 4 + wv;
            ushort4 o;
            o.x = f2bf_rne(tile[pl][lane * 4 + 0]);
            o.y = f2bf_rne(tile[pl][lane * 4 + 1]);
            o.z = f2bf_rne(tile[pl][lane * 4 + 2]);
            o.w = f2bf_rne(tile[pl][lane * 4 + 3]);
            ((ushort4*)(Abf + (size_t)(p0 + pl) * 256))[lane] = o;
        }
        if (t < 32) {
            float r[16];
#pragma unroll
            for (int j = 0; j < 16; ++j) r[j] = 0.f;
#pragma unroll
            for (int c = 0; c < 256; ++c) {
                float x  = tile[t][c];
                float sq = __fmul_rn(x, x);
                int slot = ((c >> 7) << 3) | (c & 7);
                r[slot] = __fadd_rn(r[slot], sq);
            }
            float h0 = __fadd_rn(
                __fadd_rn(__fadd_rn(r[0], r[1]), __fadd_rn(r[2], r[3])),
                __fadd_rn(__fadd_rn(r[4], r[5]), __fadd_rn(r[6], r[7])));
            float h1 = __fadd_rn(
                __fadd_rn(__fadd_rn(r[8], r[9]), __fadd_rn(r[10], r[11])),
                __fadd_rn(__fadd_rn(r[12], r[13]), __fadd_rn(r[14], r[15])));
            zsq[p0 + t] = __fadd_rn(h0, h1);
        }
        if (blk == 0 && t == 0) { *lossAcc = 0.0; *doneCnt = 0u; }
    } else {
        int k = (blk - 512) * 256 + t;
        const float* ep = emb + (size_t)k * DDIM;
        ushort4* eb = (ushort4*)(Ebf + (size_t)k * DDIM);
        float r[16];
#pragma unroll
        for (int j = 0; j < 16; ++j) r[j] = 0.f;
#pragma unroll
        for (int c4 = 0; c4 < 64; ++c4) {
            float4 v = ((const float4*)ep)[c4];
            ushort4 o;
            o.x = f2bf_rne(v.x); o.y = f2bf_rne(v.y);
            o.z = f2bf_rne(v.z); o.w = f2bf_rne(v.w);
            eb[c4] = o;
            int c = c4 * 4;
            { int slot = ((c >> 7) << 3) | (c & 7);
              r[slot] = __fadd_rn(r[slot], __fmul_rn(v.x, v.x)); }
            { int cc = c + 1; int slot = ((cc >> 7) << 3) | (cc & 7);
              r[slot] = __fadd_rn(r[slot], __fmul_rn(v.y, v.y)); }
            { int cc = c + 2; int slot = ((cc >> 7) << 3) | (cc & 7);
              r[slot] = __fadd_rn(r[slot], __fmul_rn(v.z, v.z)); }
            { int cc = c + 3; int slot = ((cc >> 7) << 3) | (cc & 7);
              r[slot] = __fadd_rn(r[slot], __fmul_rn(v.w, v.w)); }
        }
        float h0 = __fadd_rn(
            __fadd_rn(__fadd_rn(r[0], r[1]), __fadd_rn(r[2], r[3])),
            __fadd_rn(__fadd_rn(r[4], r[5]), __fadd_rn(r[6], r[7])));
        float h1 = __fadd_rn(
            __fadd_rn(__fadd_rn(r[8], r[9]), __fadd_rn(r[10], r[11])),
            __fadd_rn(__fadd_rn(r[12], r[13]), __fadd_rn(r[14], r[15])));
        esq[k] = __fadd_rn(h0, h1);
    }
}

// ---------------------------------------------------------------- kernel 2
// bf16 MFMA GEMM — exact R5 structure (256 thr, 128x128 tile, BK=32, dbuf
// DMA staging, uint2-plane LDS two-phase top-2 epilogue). Measured 118 us.
__global__ __launch_bounds__(256) void mfma_score_kernel(
        const unsigned short* __restrict__ Abf,
        const unsigned short* __restrict__ Ebf,
        const float* __restrict__ esq,
        unsigned int* __restrict__ keys) {
    union SM {
        struct { unsigned short As[2][4096]; unsigned short Bs[2][4096]; } k;
        struct { uint2 ep[128][33]; } e;   // 33792 B, aliases staging
    };
    __shared__ SM sm;
    __shared__ float sEp[128];
    __shared__ uint2 pb[128][2];

    const int nb = blockIdx.x;     // candidate block 0..63
    const int mb = blockIdx.y;     // pixel block 0..127
    const int t = threadIdx.x;
    const int w = t >> 6, lane = t & 63;
    const int wm = w >> 1, wn = w & 1;
    const int quad = lane >> 4, l16 = lane & 15;

    if (t < 128)
        sEp[t] = (esq[nb * 128 + t] + 0.125f) * 2097152.0f;  // (esq+1/8)*2^21

    // staging chunks: chunk c -> row=c>>2, slot=c&3 holds global sub=slot^swz(row)
    const int c0 = t, c1 = t + 256;
    const int r0 = c0 >> 2, s0 = (c0 & 3) ^ ((r0 ^ (r0 >> 2)) & 3);
    const int r1 = c1 >> 2, s1 = (c1 & 3) ^ ((r1 ^ (r1 >> 2)) & 3);

    const unsigned short* Ag = Abf + (size_t)(mb * 128) * 256;
    const unsigned short* Eg = Ebf + (size_t)(nb * 128) * 256;
    const unsigned short* a0g = Ag + (size_t)r0 * 256 + s0 * 8;
    const unsigned short* a1g = Ag + (size_t)r1 * 256 + s1 * 8;
    const unsigned short* e0g = Eg + (size_t)r0 * 256 + s0 * 8;
    const unsigned short* e1g = Eg + (size_t)r1 * 256 + s1 * 8;

    f32x4 acc[4][4];
#pragma unroll
    for (int i = 0; i < 4; ++i)
#pragma unroll
        for (int j = 0; j < 4; ++j)
#pragma unroll
            for (int r = 0; r < 4; ++r) acc[i][j][r] = 0.f;

    // prologue: DMA iter 0 into buffer 0
    async16(a0g, &sm.k.As[0][c0 * 8]);
    async16(a1g, &sm.k.As[0][c1 * 8]);
    async16(e0g, &sm.k.Bs[0][c0 * 8]);
    async16(e1g, &sm.k.Bs[0][c1 * 8]);

#pragma unroll
    for (int it = 0; it < 8; ++it) {
        const int cur = it & 1, nxt = cur ^ 1;
        __syncthreads();
        if (it < 7) {
            const int k0n = (it + 1) * 32;
            async16(a0g + k0n, &sm.k.As[nxt][c0 * 8]);
            async16(a1g + k0n, &sm.k.As[nxt][c1 * 8]);
            async16(e0g + k0n, &sm.k.Bs[nxt][c0 * 8]);
            async16(e1g + k0n, &sm.k.Bs[nxt][c1 * 8]);
        }
        s16x8 af[4], bfr[4];
#pragma unroll
        for (int fi = 0; fi < 4; ++fi) {
            int row  = wm * 64 + fi * 16 + l16;
            int slot = quad ^ ((row ^ (row >> 2)) & 3);
            af[fi] = *(const s16x8*)&sm.k.As[cur][row * 32 + slot * 8];
        }
#pragma unroll
        for (int fj = 0; fj < 4; ++fj) {
            int row  = wn * 64 + fj * 16 + l16;
            int slot = quad ^ ((row ^ (row >> 2)) & 3);
            bfr[fj] = *(const s16x8*)&sm.k.Bs[cur][row * 32 + slot * 8];
        }
#pragma unroll
        for (int fi = 0; fi < 4; ++fi)
#pragma unroll
            for (int fj = 0; fj < 4; ++fj)
                acc[fi][fj] = __builtin_amdgcn_mfma_f32_16x16x32_bf16(
                    af[fi], bfr[fj], acc[fi][fj], 0, 0, 0);
    }

    __syncthreads();   // K-loop LDS reads done; safe to alias staging as planes

    float epv[4];
    unsigned idxc[4];
#pragma unroll
    for (int fj = 0; fj < 4; ++fj) {
        int nloc = wn * 64 + fj * 16 + l16;
        epv[fj]  = sEp[nloc];
        idxc[fj] = (unsigned)(nb * 128 + nloc);
    }

    // phase A: per (fi,r) pack 4 keys, sort4 -> top2, one ds_write_b64
#pragma unroll
    for (int fi = 0; fi < 4; ++fi) {
#pragma unroll
        for (int r = 0; r < 4; ++r) {
            unsigned kk[4];
#pragma unroll
            for (int fj = 0; fj < 4; ++fj) {
                unsigned u = (unsigned)fmaf(acc[fi][fj][r], -4194304.0f, epv[fj]);
                kk[fj] = (u << 13) | idxc[fj];
            }
            unsigned lo0 = min(kk[0], kk[1]), hi0 = max(kk[0], kk[1]);
            unsigned lo1 = min(kk[2], kk[3]), hi1 = max(kk[2], kk[3]);
            unsigned a0 = min(lo0, lo1);
            unsigned a1 = min(max(lo0, lo1), min(hi0, hi1));
            int row = wm * 64 + fi * 16 + quad * 4 + r;
            sm.e.ep[row][wn * 16 + l16] = make_uint2(a0, a1);
        }
    }
    __syncthreads();

    // phase B1: 2 threads per row scan 16 entries each
    {
        int row = t >> 1, h0 = (t & 1) * 16;
        uint2 mv = sm.e.ep[row][h0];
#pragma unroll
        for (int i = 1; i < 16; ++i) {
            uint2 av = sm.e.ep[row][h0 + i];
            unsigned n0 = min(mv.x, av.x);
            unsigned n1 = min(max(mv.x, av.x), min(mv.y, av.y));
            mv.x = n0; mv.y = n1;
        }
        pb[row][t & 1] = mv;
    }
    __syncthreads();

    // phase B2: combine halves, write pixel-major keys
    if (t < 128) {
        uint2 x = pb[t][0], y = pb[t][1];
        unsigned n0 = min(x.x, y.x);
        unsigned n1 = min(max(x.x, y.x), min(x.y, y.y));
        ((uint2*)keys)[(size_t)(mb * 128 + t) * 64 + nb] = make_uint2(n0, n1);
    }
}

// ---------------------------------------------------------------- kernel 3
// Fused (R5 structure, 512 blocks of 32 pixels): LDS z-tile, keys min +
// margin candidates (ballot), exact rescore (fp64 dot -> np fp32), idx out,
// gather emb[idx] -> out, loss accumulation + last-block loss finalize.
__global__ __launch_bounds__(256) void final_kernel(
        const unsigned int* __restrict__ keys,
        const float* __restrict__ z, const float* __restrict__ emb,
        const float* __restrict__ zsq, const float* __restrict__ esq,
        float* __restrict__ out, float* __restrict__ idx_out,
        float* __restrict__ loss_out,
        double* __restrict__ lossAcc, unsigned* __restrict__ doneCnt) {
    __shared__ float ztile[32][260];
    __shared__ int sidx[32];
    int blk = blockIdx.x;            // 0..511
    int b = blk >> 5, h = blk & 31;
    int t = threadIdx.x;
    int p0 = b * 1024 + h * 32;
    const float* zb = z + (size_t)b * 262144 + h * 32;
    {
        int px = t & 31, cb = t >> 5;
#pragma unroll
        for (int cc = 0; cc < 32; ++cc) {
            int c = cc * 8 + cb;
            ztile[px][c] = zb[(size_t)c * 1024 + px];
        }
    }
    __syncthreads();

    int wq = t >> 6, lane = t & 63;
    const uint2* kp = (const uint2*)keys;
#pragma unroll 1
    for (int i = 0; i < 8; ++i) {
        int px = wq * 8 + i;
        int p  = p0 + px;
        uint2 kv = kp[(size_t)p * 64 + lane];
        unsigned m = min(kv.x, kv.y);
#pragma unroll
        for (int off = 32; off >= 1; off >>= 1)
            m = min(m, (unsigned)__shfl_xor((int)m, off, 64));
        unsigned thr = (m >> 13) + 512;   // margin 512*2^-21 = 2.44e-4
        unsigned long long m0 = __ballot((kv.x >> 13) <= thr);
        unsigned long long m1 = __ballot((kv.y >> 13) <= thr);
        float4 zv = *(const float4*)&ztile[px][lane * 4];
        float zs = zsq[p];
        unsigned long long best = ~0ull;
        while (m0 | m1) {
            bool use0 = (m0 != 0);
            unsigned long long mm = use0 ? m0 : m1;
            int src = (int)__builtin_ctzll(mm);
            if (use0) m0 &= m0 - 1; else m1 &= m1 - 1;
            unsigned keyv = (unsigned)__shfl((int)(use0 ? kv.x : kv.y), src, 64);
            int k = (int)(keyv & 0x1FFFu);
            const float4 ev = *(const float4*)(emb + (size_t)k * DDIM + lane * 4);
            double d = (double)zv.x * ev.x + (double)zv.y * ev.y
                     + (double)zv.z * ev.z + (double)zv.w * ev.w;
#pragma unroll
            for (int off = 32; off >= 1; off >>= 1)
                d += __shfl_down(d, off, 64);
            d = __shfl(d, 0, 64);
            float df = (float)d;
            float s  = __fsub_rn(__fadd_rn(zs, esq[k]), __fmul_rn(2.0f, df));
            unsigned long long key =
                ((unsigned long long)f32_sortable(s) << 32) | (unsigned)k;
            best = key < best ? key : best;
        }
        if (lane == 0) {
            int k = (int)(unsigned)(best & 0xffffffffu);
            sidx[px] = k;
            idx_out[p] = (float)k;
        }
    }
    __syncthreads();

    // gather + loss (z from LDS)
    int wq2 = t & 31, cy = t >> 5;
    int kk = sidx[wq2];
    const float* er = emb + (size_t)kk * DDIM;
    float* ob = out + (size_t)b * 262144 + h * 32;
    float local = 0.f;
#pragma unroll 4
    for (int it = 0; it < 32; ++it) {
        int c = it * 8 + cy;
        float q = er[c];
        float d = q - ztile[wq2][c];
        ob[(size_t)c * 1024 + wq2] = q;
        local += d * d;
    }
#pragma unroll
    for (int off = 32; off >= 1; off >>= 1) local += __shfl_down(local, off, 64);
    __shared__ float wsum[4];
    if ((t & 63) == 0) wsum[t >> 6] = local;
    __syncthreads();
    if (t == 0) {
        double s = (double)wsum[0] + (double)wsum[1]
                 + (double)wsum[2] + (double)wsum[3];
        atomicAdd(lossAcc, s);
        __threadfence();
        unsigned old = atomicAdd(doneCnt, 1u);
        if (old == 511u) {
            double tot = atomicAdd(lossAcc, 0.0);  // coherent device-scope read
            *loss_out = (float)(tot * (1.25 / 4194304.0));
        }
    }
}

// ----------------------------------------------------------------
extern "C" void kernel_launch(void* const* d_in, const int* in_sizes, int n_in,
                              void* d_out, int out_size, void* d_ws, size_t ws_size,
                              hipStream_t stream) {
    const float* z   = (const float*)d_in[0];
    const float* emb = (const float*)d_in[1];
    float* out = (float*)d_out;
    char* ws = (char*)d_ws;

    unsigned short* Abf = (unsigned short*)(ws + WS_ABF);
    unsigned short* Ebf = (unsigned short*)(ws + WS_EBF);
    unsigned int*  keys = (unsigned int*)(ws + WS_KEYS);
    float* zsq      = (float*)(ws + WS_ZSQ);
    float* esq      = (float*)(ws + WS_ESQ);
    double* lossAcc = (double*)(ws + WS_LOSS);
    unsigned* doneCnt = (unsigned*)(ws + WS_CNT);

    prep_kernel<<<544, 256, 0, stream>>>(z, emb, Abf, Ebf, zsq, esq,
                                         lossAcc, doneCnt);
    mfma_score_kernel<<<dim3(64, 128), 256, 0, stream>>>(Abf, Ebf, esq, keys);
    final_kernel<<<512, 256, 0, stream>>>(keys, z, emb, zsq, esq,
                                          out, out + 4194305, out + 4194304,
                                          lossAcc, doneCnt);
}